// Round 4
// baseline (322.195 us; speedup 1.0000x reference)
//
#include <hip/hip_runtime.h>
#include <hip/hip_bf16.h>
#include <stdint.h>

#define IN_F   4096
#define OUT_F  768
#define OUTB   (OUT_F * 8)       // 6144
#define BATCH  1024
#define SPLITK 4
#define KSPAN  (IN_F / SPLITK)   // 1024
#define BK     64
#define NIT    (KSPAN / BK)      // 16
#define PLANE  (BATCH * OUT_F)   // 786432
#define NTILE  192               // 12 n-tiles x 16 m-tiles

typedef short short8  __attribute__((ext_vector_type(8)));
typedef float f32x4   __attribute__((ext_vector_type(4)));
typedef unsigned int u32;

// ws layout (bytes):
//   0        : predp   float[4][PLANE]     split-K partial planes (12.58 MB)
//   12582912 : wp      ushort[IN_F*OUT_F]  packed [(k/8)][n][k%8]  (6.29 MB)
//   18874368 : labf    ushort[BATCH*IN_F]  bf16 latent row-major   (8.39 MB)
//   27262976 : regpart float[1536]
//   27269120 : sqpart  float[192]
//   27269888 : tileCnt int[192]; tilesDone int   (zeroed by k_weights each call)
#define WS_WP    12582912
#define WS_LABF  18874368
#define WS_REGP  27262976
#define WS_SQP   27269120
#define WS_CNT   27269888

__device__ __forceinline__ ushort f2bf(float f) {
    uint32_t u = __builtin_bit_cast(uint32_t, f);
    u += 0x7FFFu + ((u >> 16) & 1u);
    return (ushort)(u >> 16);
}

__device__ __forceinline__ float waveReduceSum(float v) {
    #pragma unroll
    for (int off = 32; off > 0; off >>= 1) v += __shfl_down(v, off, 64);
    return v;
}

__device__ __forceinline__ void glds16(const void* g, void* l) {
    __builtin_amdgcn_global_load_lds(
        (const __attribute__((address_space(1))) u32*)g,
        (__attribute__((address_space(3))) u32*)l, 16, 0, 0);
}

// k_weights: blocks [0,1536): int_weights (bf16 packed) + reg partials.
//            blocks [1536,2048): latent fp32->bf16 (rides the HBM-bound dispatch).
//            block 0 additionally zeroes the inter-block counters for k_gemm.
__global__ __launch_bounds__(256) void k_weights(const float* __restrict__ w,
                                                 const float* __restrict__ latent,
                                                 ushort* __restrict__ wp,
                                                 ushort* __restrict__ labf,
                                                 float* __restrict__ regpart,
                                                 int* __restrict__ cnt) {
    if (blockIdx.x == 0 && threadIdx.x < 200) cnt[threadIdx.x] = 0;  // tileCnt[192]+tilesDone

    if (blockIdx.x >= 1536) {
        int t = (blockIdx.x - 1536) * 256 + threadIdx.x;
        const float4* src = (const float4*)latent;
        uint4* dst = (uint4*)labf;
        #pragma unroll
        for (int j = 0; j < 4; j++) {
            int o = j * 131072 + t;
            float4 a0 = src[2 * o];
            float4 a1 = src[2 * o + 1];
            union { ushort u[8]; uint4 v; } pk;
            pk.u[0] = f2bf(a0.x); pk.u[1] = f2bf(a0.y); pk.u[2] = f2bf(a0.z); pk.u[3] = f2bf(a0.w);
            pk.u[4] = f2bf(a1.x); pk.u[5] = f2bf(a1.y); pk.u[6] = f2bf(a1.z); pk.u[7] = f2bf(a1.w);
            dst[o] = pk.v;
        }
        return;
    }

    int t  = blockIdx.x * 256 + threadIdx.x;
    int o  = t % OUT_F;
    int i8 = t / OUT_F;
    const float* src = w + (size_t)(i8 * 8) * OUTB + (size_t)o * 8;

    const float P[8] = {1.f, 2.f, 4.f, 8.f, 16.f, 32.f, 64.f, -128.f};
    float regsum = 0.f;
    union { ushort u[8]; uint4 v; } pk;

    #pragma unroll
    for (int r = 0; r < 8; r++) {
        float4 a = *(const float4*)(src + (size_t)r * OUTB);
        float4 b = *(const float4*)(src + (size_t)r * OUTB + 4);
        float x[8] = {a.x, a.y, a.z, a.w, b.x, b.y, b.z, b.w};
        float iw = 0.f;
        #pragma unroll
        for (int j = 0; j < 8; j++) {
            float p = __builtin_amdgcn_rcpf(1.f + __expf(-x[j]));
            iw += p * P[j];
            regsum += fminf(p, 1.f - p);
        }
        pk.u[r] = f2bf(iw);
    }
    *(uint4*)(wp + ((size_t)i8 * OUT_F + o) * 8) = pk.v;

    float ws = waveReduceSum(regsum);
    __shared__ float red[4];
    int lane = threadIdx.x & 63, wv = threadIdx.x >> 6;
    if (lane == 0) red[wv] = ws;
    __syncthreads();
    if (threadIdx.x == 0) regpart[blockIdx.x] = red[0] + red[1] + red[2] + red[3];
}

// k_gemm: split-K bf16 MFMA GEMM (64x64 tile, BK=64, double-buffered, B via
// global_load_lds) + in-kernel split-K fixup: last z-block per tile computes the
// squared-error partial; last tile-finisher reduces everything and writes out.
__global__ __launch_bounds__(256) void k_gemm(const ushort* __restrict__ labf,
                                              const ushort* __restrict__ wp,
                                              const float* __restrict__ tsum,
                                              float* __restrict__ predp,
                                              const float* __restrict__ regpart,
                                              float* __restrict__ sqpart,
                                              int* __restrict__ tileCnt,
                                              int* __restrict__ tilesDone,
                                              float* __restrict__ out) {
    __shared__ __align__(16) ushort lA[2][64 * 72];   // row stride 72
    __shared__ __align__(16) ushort lB[2][8 * 1032];  // plane stride 1032

    const int tid  = threadIdx.x;
    const int n0   = blockIdx.x * 64;
    const int m0   = blockIdx.y * 64;
    const int bz   = blockIdx.z;
    const int kbase = bz * KSPAN;
    const int kg0   = kbase >> 3;
    const int lane = tid & 63, w = tid >> 6;
    const int wm = w >> 1, wn = w & 1;
    const int quad = lane >> 4, l16 = lane & 15;

    f32x4 acc[2][2] = {{{0.f,0.f,0.f,0.f},{0.f,0.f,0.f,0.f}},
                       {{0.f,0.f,0.f,0.f},{0.f,0.f,0.f,0.f}}};

    const int ar = tid >> 2, ac = tid & 3;            // A: row, 16-elem k-chunk
    const ushort* aptr = labf + (size_t)(m0 + ar) * IN_F + kbase + ac * 16;
    const ushort* bbase = wp + ((size_t)kg0 * OUT_F + n0 + lane) * 8;

    int buf = 0;
    // prologue: stage iter 0
    glds16(bbase + (size_t)(2 * w) * OUT_F * 8,     &lB[0][(2 * w) * 1032]);
    glds16(bbase + (size_t)(2 * w + 1) * OUT_F * 8, &lB[0][(2 * w + 1) * 1032]);
    {
        uint4 a0 = *(const uint4*)aptr;
        uint4 a1 = *(const uint4*)(aptr + 8);
        *(uint4*)&lA[0][ar * 72 + ac * 16]     = a0;
        *(uint4*)&lA[0][ar * 72 + ac * 16 + 8] = a1;
    }
    __syncthreads();

    for (int it = 0; it < NIT; ++it) {
        const int nxt = buf ^ 1;
        uint4 a0, a1;
        if (it + 1 < NIT) {
            const ushort* bp = bbase + (size_t)(it + 1) * 8 * OUT_F * 8;
            glds16(bp + (size_t)(2 * w) * OUT_F * 8,     &lB[nxt][(2 * w) * 1032]);
            glds16(bp + (size_t)(2 * w + 1) * OUT_F * 8, &lB[nxt][(2 * w + 1) * 1032]);
            a0 = *(const uint4*)(aptr + (it + 1) * BK);
            a1 = *(const uint4*)(aptr + (it + 1) * BK + 8);
        }
        #pragma unroll
        for (int s = 0; s < 2; ++s) {
            short8 af0 = *(short8*)&lA[buf][(wm * 32 + l16) * 72 + s * 32 + quad * 8];
            short8 af1 = *(short8*)&lA[buf][(wm * 32 + 16 + l16) * 72 + s * 32 + quad * 8];
            short8 bf0 = *(short8*)&lB[buf][(s * 4 + quad) * 1032 + (wn * 32 + l16) * 8];
            short8 bf1 = *(short8*)&lB[buf][(s * 4 + quad) * 1032 + (wn * 32 + 16 + l16) * 8];
            acc[0][0] = __builtin_amdgcn_mfma_f32_16x16x32_bf16(af0, bf0, acc[0][0], 0, 0, 0);
            acc[0][1] = __builtin_amdgcn_mfma_f32_16x16x32_bf16(af0, bf1, acc[0][1], 0, 0, 0);
            acc[1][0] = __builtin_amdgcn_mfma_f32_16x16x32_bf16(af1, bf0, acc[1][0], 0, 0, 0);
            acc[1][1] = __builtin_amdgcn_mfma_f32_16x16x32_bf16(af1, bf1, acc[1][1], 0, 0, 0);
        }
        if (it + 1 < NIT) {
            *(uint4*)&lA[nxt][ar * 72 + ac * 16]     = a0;
            *(uint4*)&lA[nxt][ar * 72 + ac * 16 + 8] = a1;
        }
        __syncthreads();
        buf = nxt;
    }

    // store split-K partial plane (disjoint, coalesced)
    float* plane = predp + (size_t)bz * PLANE;
    #pragma unroll
    for (int fm = 0; fm < 2; fm++)
    #pragma unroll
    for (int fn = 0; fn < 2; fn++)
    #pragma unroll
    for (int r = 0; r < 4; r++) {
        int m = m0 + wm * 32 + fm * 16 + quad * 4 + r;
        int n = n0 + wn * 32 + fn * 16 + l16;
        plane[(size_t)m * OUT_F + n] = acc[fm][fn][r];
    }

    // --- split-K fixup: release-fence, then count z-blocks for this tile
    __threadfence();
    const int tileIdx = blockIdx.y * 12 + blockIdx.x;
    __shared__ int sdone;
    if (tid == 0) sdone = atomicAdd(&tileCnt[tileIdx], 1);
    __syncthreads();
    if (sdone != SPLITK - 1) return;

    // last z-block of this tile: acquire, sum 4 planes + squared error vs int_sum
    __threadfence();
    const int nl = tid & 63;
    const int mg = tid >> 6;
    float lsum = 0.f;
    #pragma unroll 4
    for (int r = 0; r < 16; ++r) {
        int m = m0 + mg * 16 + r;
        int n = n0 + nl;
        size_t idx = (size_t)m * OUT_F + n;
        float p = predp[idx] + predp[idx + PLANE] + predp[idx + 2 * PLANE] + predp[idx + 3 * PLANE];
        const float* ts = tsum + (size_t)m * OUTB + (size_t)n * 8;
        float4 t0 = *(const float4*)ts;
        float4 t1 = *(const float4*)(ts + 4);
        float isum = t0.x + 2.f * t0.y + 4.f * t0.z + 8.f * t0.w
                   + 16.f * t1.x + 32.f * t1.y + 64.f * t1.z - 128.f * t1.w;
        float d = p - isum;
        lsum += d * d;
    }
    float wsum = waveReduceSum(lsum);
    __shared__ float redS[4];
    if ((tid & 63) == 0) redS[tid >> 6] = wsum;
    __syncthreads();
    __shared__ int sfin;
    if (tid == 0) {
        sqpart[tileIdx] = redS[0] + redS[1] + redS[2] + redS[3];
        __threadfence();
        sfin = (atomicAdd(tilesDone, 1) == NTILE - 1);
    }
    __syncthreads();
    if (!sfin) return;

    // global finisher: reduce regpart[1536] + sqpart[192], write the 3 outputs
    __threadfence();
    float r = 0.f;
    #pragma unroll
    for (int j = 0; j < 6; ++j) r += regpart[tid + j * 256];
    float s = (tid < NTILE) ? sqpart[tid] : 0.f;
    r = waveReduceSum(r);
    s = waveReduceSum(s);
    __shared__ float redR2[4], redS2[4];
    if ((tid & 63) == 0) { redR2[tid >> 6] = r; redS2[tid >> 6] = s; }
    __syncthreads();
    if (tid == 0) {
        float R = redR2[0] + redR2[1] + redR2[2] + redR2[3];
        float S = redS2[0] + redS2[1] + redS2[2] + redS2[3];
        float recon = S / ((float)(BATCH * OUT_F) * 255.f * 255.f);
        float reg   = 0.001f * R / (float)((size_t)IN_F * OUTB);
        out[0] = recon + reg;
        out[1] = recon;
        out[2] = reg;
    }
}

extern "C" void kernel_launch(void* const* d_in, const int* in_sizes, int n_in,
                              void* d_out, int out_size, void* d_ws, size_t ws_size,
                              hipStream_t stream) {
    const float* latent = (const float*)d_in[0];   // [1024, 4096]
    const float* tsum   = (const float*)d_in[1];   // [1024, 6144]
    const float* weight = (const float*)d_in[2];   // [4096, 6144]
    float* out      = (float*)d_out;
    float* predp    = (float*)d_ws;
    ushort* wp      = (ushort*)((char*)d_ws + WS_WP);
    ushort* labf    = (ushort*)((char*)d_ws + WS_LABF);
    float* regpart  = (float*)((char*)d_ws + WS_REGP);
    float* sqpart   = (float*)((char*)d_ws + WS_SQP);
    int*   cnt      = (int*)((char*)d_ws + WS_CNT);     // tileCnt[192]; tilesDone

    k_weights<<<2048, 256, 0, stream>>>(weight, latent, wp, labf, regpart, cnt);
    k_gemm<<<dim3(OUT_F / 64, BATCH / 64, SPLITK), 256, 0, stream>>>(
        labf, wp, tsum, predp, regpart, sqpart, cnt, cnt + NTILE, out);
}

// Round 5
// 268.243 us; speedup vs baseline: 1.2011x; 1.2011x over previous
//
#include <hip/hip_runtime.h>
#include <hip/hip_bf16.h>
#include <stdint.h>

#define IN_F   4096
#define OUT_F  768
#define OUTB   (OUT_F * 8)       // 6144
#define BATCH  1024
#define SPLITK 4
#define KSPAN  (IN_F / SPLITK)   // 1024
#define BK     64
#define NIT    (KSPAN / BK)      // 16
#define PLANE  (BATCH * OUT_F)   // 786432
#define EPIBLKS 3072             // k_epi grid (3,1024)

typedef short short8  __attribute__((ext_vector_type(8)));
typedef float f32x4   __attribute__((ext_vector_type(4)));
typedef unsigned int u32;

// ws layout (bytes):
//   0        : predp   float[4][PLANE]     split-K partial planes (12.58 MB)
//   12582912 : wp      ushort[IN_F*OUT_F]  packed [(k/8)][n][k%8]  (6.29 MB)
//   18874368 : labf    ushort[BATCH*IN_F]  bf16 latent row-major   (8.39 MB)
//   27262976 : regpart float[1536]
//   27269120 : accum   float[1]  (sq sum, atomic)
//   27269124 : cnt     int[1]    (k_epi ticket)
#define WS_WP    12582912
#define WS_LABF  18874368
#define WS_REGP  27262976
#define WS_ACC   27269120
#define WS_CNT   27269124

__device__ __forceinline__ ushort f2bf(float f) {
    uint32_t u = __builtin_bit_cast(uint32_t, f);
    u += 0x7FFFu + ((u >> 16) & 1u);
    return (ushort)(u >> 16);
}

__device__ __forceinline__ float waveReduceSum(float v) {
    #pragma unroll
    for (int off = 32; off > 0; off >>= 1) v += __shfl_down(v, off, 64);
    return v;
}

__device__ __forceinline__ void glds16(const void* g, void* l) {
    __builtin_amdgcn_global_load_lds(
        (const __attribute__((address_space(1))) u32*)g,
        (__attribute__((address_space(3))) u32*)l, 16, 0, 0);
}

// k_weights: blocks [0,1536): int_weights (bf16 packed) + reg partials.
//            blocks [1536,2048): latent fp32->bf16 conversion.
//            block 0 zeroes accum/cnt for k_epi (visible at dispatch boundary).
__global__ __launch_bounds__(256) void k_weights(const float* __restrict__ w,
                                                 const float* __restrict__ latent,
                                                 ushort* __restrict__ wp,
                                                 ushort* __restrict__ labf,
                                                 float* __restrict__ regpart,
                                                 float* __restrict__ accum,
                                                 int* __restrict__ cnt) {
    if (blockIdx.x == 0 && threadIdx.x == 0) { accum[0] = 0.f; cnt[0] = 0; }

    if (blockIdx.x >= 1536) {
        int t = (blockIdx.x - 1536) * 256 + threadIdx.x;
        const float4* src = (const float4*)latent;
        uint4* dst = (uint4*)labf;
        #pragma unroll
        for (int j = 0; j < 4; j++) {
            int o = j * 131072 + t;
            float4 a0 = src[2 * o];
            float4 a1 = src[2 * o + 1];
            union { ushort u[8]; uint4 v; } pk;
            pk.u[0] = f2bf(a0.x); pk.u[1] = f2bf(a0.y); pk.u[2] = f2bf(a0.z); pk.u[3] = f2bf(a0.w);
            pk.u[4] = f2bf(a1.x); pk.u[5] = f2bf(a1.y); pk.u[6] = f2bf(a1.z); pk.u[7] = f2bf(a1.w);
            dst[o] = pk.v;
        }
        return;
    }

    int t  = blockIdx.x * 256 + threadIdx.x;
    int o  = t % OUT_F;
    int i8 = t / OUT_F;
    const float* src = w + (size_t)(i8 * 8) * OUTB + (size_t)o * 8;

    const float P[8] = {1.f, 2.f, 4.f, 8.f, 16.f, 32.f, 64.f, -128.f};
    float regsum = 0.f;
    union { ushort u[8]; uint4 v; } pk;

    #pragma unroll
    for (int r = 0; r < 8; r++) {
        float4 a = *(const float4*)(src + (size_t)r * OUTB);
        float4 b = *(const float4*)(src + (size_t)r * OUTB + 4);
        float x[8] = {a.x, a.y, a.z, a.w, b.x, b.y, b.z, b.w};
        float iw = 0.f;
        #pragma unroll
        for (int j = 0; j < 8; j++) {
            float p = __builtin_amdgcn_rcpf(1.f + __expf(-x[j]));
            iw += p * P[j];
            regsum += fminf(p, 1.f - p);
        }
        pk.u[r] = f2bf(iw);
    }
    *(uint4*)(wp + ((size_t)i8 * OUT_F + o) * 8) = pk.v;

    float ws = waveReduceSum(regsum);
    __shared__ float red[4];
    int lane = threadIdx.x & 63, wv = threadIdx.x >> 6;
    if (lane == 0) red[wv] = ws;
    __syncthreads();
    if (threadIdx.x == 0) regpart[blockIdx.x] = red[0] + red[1] + red[2] + red[3];
}

// k_gemm: split-K bf16 MFMA GEMM, 64x64 tile, BK=64, double-buffered,
// B staged via global_load_lds. Pure disjoint plane stores — NO fences/atomics.
__global__ __launch_bounds__(256) void k_gemm(const ushort* __restrict__ labf,
                                              const ushort* __restrict__ wp,
                                              float* __restrict__ predp) {
    __shared__ __align__(16) ushort lA[2][64 * 72];   // row stride 72
    __shared__ __align__(16) ushort lB[2][8 * 1032];  // plane stride 1032

    const int tid  = threadIdx.x;
    const int n0   = blockIdx.x * 64;
    const int m0   = blockIdx.y * 64;
    const int bz   = blockIdx.z;
    const int kbase = bz * KSPAN;
    const int kg0   = kbase >> 3;
    const int lane = tid & 63, w = tid >> 6;
    const int wm = w >> 1, wn = w & 1;
    const int quad = lane >> 4, l16 = lane & 15;

    f32x4 acc[2][2] = {{{0.f,0.f,0.f,0.f},{0.f,0.f,0.f,0.f}},
                       {{0.f,0.f,0.f,0.f},{0.f,0.f,0.f,0.f}}};

    const int ar = tid >> 2, ac = tid & 3;            // A: row, 16-elem k-chunk
    const ushort* aptr = labf + (size_t)(m0 + ar) * IN_F + kbase + ac * 16;
    const ushort* bbase = wp + ((size_t)kg0 * OUT_F + n0 + lane) * 8;

    int buf = 0;
    glds16(bbase + (size_t)(2 * w) * OUT_F * 8,     &lB[0][(2 * w) * 1032]);
    glds16(bbase + (size_t)(2 * w + 1) * OUT_F * 8, &lB[0][(2 * w + 1) * 1032]);
    {
        uint4 a0 = *(const uint4*)aptr;
        uint4 a1 = *(const uint4*)(aptr + 8);
        *(uint4*)&lA[0][ar * 72 + ac * 16]     = a0;
        *(uint4*)&lA[0][ar * 72 + ac * 16 + 8] = a1;
    }
    __syncthreads();

    for (int it = 0; it < NIT; ++it) {
        const int nxt = buf ^ 1;
        uint4 a0, a1;
        if (it + 1 < NIT) {
            const ushort* bp = bbase + (size_t)(it + 1) * 8 * OUT_F * 8;
            glds16(bp + (size_t)(2 * w) * OUT_F * 8,     &lB[nxt][(2 * w) * 1032]);
            glds16(bp + (size_t)(2 * w + 1) * OUT_F * 8, &lB[nxt][(2 * w + 1) * 1032]);
            a0 = *(const uint4*)(aptr + (it + 1) * BK);
            a1 = *(const uint4*)(aptr + (it + 1) * BK + 8);
        }
        #pragma unroll
        for (int s = 0; s < 2; ++s) {
            short8 af0 = *(short8*)&lA[buf][(wm * 32 + l16) * 72 + s * 32 + quad * 8];
            short8 af1 = *(short8*)&lA[buf][(wm * 32 + 16 + l16) * 72 + s * 32 + quad * 8];
            short8 bf0 = *(short8*)&lB[buf][(s * 4 + quad) * 1032 + (wn * 32 + l16) * 8];
            short8 bf1 = *(short8*)&lB[buf][(s * 4 + quad) * 1032 + (wn * 32 + 16 + l16) * 8];
            acc[0][0] = __builtin_amdgcn_mfma_f32_16x16x32_bf16(af0, bf0, acc[0][0], 0, 0, 0);
            acc[0][1] = __builtin_amdgcn_mfma_f32_16x16x32_bf16(af0, bf1, acc[0][1], 0, 0, 0);
            acc[1][0] = __builtin_amdgcn_mfma_f32_16x16x32_bf16(af1, bf0, acc[1][0], 0, 0, 0);
            acc[1][1] = __builtin_amdgcn_mfma_f32_16x16x32_bf16(af1, bf1, acc[1][1], 0, 0, 0);
        }
        if (it + 1 < NIT) {
            *(uint4*)&lA[nxt][ar * 72 + ac * 16]     = a0;
            *(uint4*)&lA[nxt][ar * 72 + ac * 16 + 8] = a1;
        }
        __syncthreads();
        buf = nxt;
    }

    float* plane = predp + (size_t)bz * PLANE;
    #pragma unroll
    for (int fm = 0; fm < 2; fm++)
    #pragma unroll
    for (int fn = 0; fn < 2; fn++)
    #pragma unroll
    for (int r = 0; r < 4; r++) {
        int m = m0 + wm * 32 + fm * 16 + quad * 4 + r;
        int n = n0 + wn * 32 + fn * 16 + l16;
        plane[(size_t)m * OUT_F + n] = acc[fm][fn][r];
    }
}

// k_epi: grid (3,1024), one thread per (m,n). Sums 4 split-K planes, squared
// error vs int_sum; per-block partial -> device-coherent atomicAdd. Last block
// (atomic ticket, ordered by s_waitcnt — NO device fences) reduces regpart and
// writes the 3 outputs. Kills the separate k_fin dispatch.
__global__ __launch_bounds__(256) void k_epi(const float* __restrict__ predp,
                                             const float* __restrict__ tsum,
                                             const float* __restrict__ regpart,
                                             float* __restrict__ accum,
                                             int* __restrict__ cnt,
                                             float* __restrict__ out) {
    int n = blockIdx.x * 256 + threadIdx.x;
    int m = blockIdx.y;
    size_t idx = (size_t)m * OUT_F + n;
    float p = predp[idx] + predp[idx + PLANE] + predp[idx + 2 * PLANE] + predp[idx + 3 * PLANE];
    const float* ts = tsum + (size_t)m * OUTB + (size_t)n * 8;
    float4 t0 = *(const float4*)ts;
    float4 t1 = *(const float4*)(ts + 4);
    float isum = t0.x + 2.f * t0.y + 4.f * t0.z + 8.f * t0.w
               + 16.f * t1.x + 32.f * t1.y + 64.f * t1.z - 128.f * t1.w;
    float d = p - isum;

    float wsum = waveReduceSum(d * d);
    __shared__ float red[4];
    if ((threadIdx.x & 63) == 0) red[threadIdx.x >> 6] = wsum;
    __syncthreads();
    __shared__ int slast;
    if (threadIdx.x == 0) {
        atomicAdd(accum, red[0] + red[1] + red[2] + red[3]);
        __asm__ volatile("s_waitcnt vmcnt(0)" ::: "memory");   // order: add before ticket
        slast = (atomicAdd(cnt, 1) == EPIBLKS - 1);
    }
    __syncthreads();
    if (!slast) return;

    // finisher: all prior accum-adds complete (ticket ordering). Coherent read
    // via atomic; regpart written 2 dispatches ago (visible via dispatch boundary).
    float r = 0.f;
    #pragma unroll
    for (int j = 0; j < 6; ++j) r += regpart[threadIdx.x + j * 256];
    r = waveReduceSum(r);
    __shared__ float redR[4];
    if ((threadIdx.x & 63) == 0) redR[threadIdx.x >> 6] = r;
    __syncthreads();
    if (threadIdx.x == 0) {
        float R = redR[0] + redR[1] + redR[2] + redR[3];
        float S = atomicAdd(accum, 0.f);                       // coherent read
        float recon = S / ((float)(BATCH * OUT_F) * 255.f * 255.f);
        float reg   = 0.001f * R / (float)((size_t)IN_F * OUTB);
        out[0] = recon + reg;
        out[1] = recon;
        out[2] = reg;
    }
}

extern "C" void kernel_launch(void* const* d_in, const int* in_sizes, int n_in,
                              void* d_out, int out_size, void* d_ws, size_t ws_size,
                              hipStream_t stream) {
    const float* latent = (const float*)d_in[0];   // [1024, 4096]
    const float* tsum   = (const float*)d_in[1];   // [1024, 6144]
    const float* weight = (const float*)d_in[2];   // [4096, 6144]
    float* out      = (float*)d_out;
    float* predp    = (float*)d_ws;
    ushort* wp      = (ushort*)((char*)d_ws + WS_WP);
    ushort* labf    = (ushort*)((char*)d_ws + WS_LABF);
    float* regpart  = (float*)((char*)d_ws + WS_REGP);
    float* accum    = (float*)((char*)d_ws + WS_ACC);
    int*   cnt      = (int*)((char*)d_ws + WS_CNT);

    k_weights<<<2048, 256, 0, stream>>>(weight, latent, wp, labf, regpart, accum, cnt);
    k_gemm<<<dim3(OUT_F / 64, BATCH / 64, SPLITK), 256, 0, stream>>>(labf, wp, predp);
    k_epi<<<dim3(3, BATCH), 256, 0, stream>>>(predp, tsum, regpart, accum, cnt, out);
}

// Round 6
// 200.859 us; speedup vs baseline: 1.6041x; 1.3355x over previous
//
#include <hip/hip_runtime.h>
#include <hip/hip_bf16.h>
#include <stdint.h>

#define IN_F   4096
#define OUT_F  768
#define OUTB   (OUT_F * 8)       // 6144
#define BATCH  1024
#define SPLITK 4
#define KSPAN  (IN_F / SPLITK)   // 1024
#define BK     64
#define NIT    (KSPAN / BK)      // 16
#define PLANE  (BATCH * OUT_F)   // 786432 floats
#define PLANE4 (PLANE / 4)       // 196608 float4
#define EPIBLK 768               // k_epi blocks (plain-store partials)

typedef short short8  __attribute__((ext_vector_type(8)));
typedef float f32x4   __attribute__((ext_vector_type(4)));
typedef unsigned int u32;

// ws layout (bytes):
//   0        : predp   float[4][PLANE]     split-K partial planes (12.58 MB)
//   12582912 : wp      ushort[IN_F*OUT_F]  packed [(k/8)][n][k%8]  (6.29 MB)
//   18874368 : labf    ushort[BATCH*IN_F]  bf16 latent row-major   (8.39 MB)
//   27262976 : regpart float[1536]
//   27269120 : sqpart  float[768]
#define WS_WP    12582912
#define WS_LABF  18874368
#define WS_REGP  27262976
#define WS_SQP   27269120

__device__ __forceinline__ ushort f2bf(float f) {
    uint32_t u = __builtin_bit_cast(uint32_t, f);
    u += 0x7FFFu + ((u >> 16) & 1u);
    return (ushort)(u >> 16);
}

__device__ __forceinline__ float waveReduceSum(float v) {
    #pragma unroll
    for (int off = 32; off > 0; off >>= 1) v += __shfl_down(v, off, 64);
    return v;
}

__device__ __forceinline__ void glds16(const void* g, void* l) {
    __builtin_amdgcn_global_load_lds(
        (const __attribute__((address_space(1))) u32*)g,
        (__attribute__((address_space(3))) u32*)l, 16, 0, 0);
}

// k_weights: blocks [0,1536): int_weights (bf16 packed [(k/8)][n][k%8]) + reg
// partials. blocks [1536,2048): latent fp32->bf16 conversion (rides along).
__global__ __launch_bounds__(256) void k_weights(const float* __restrict__ w,
                                                 const float* __restrict__ latent,
                                                 ushort* __restrict__ wp,
                                                 ushort* __restrict__ labf,
                                                 float* __restrict__ regpart) {
    if (blockIdx.x >= 1536) {
        int t = (blockIdx.x - 1536) * 256 + threadIdx.x;
        const float4* src = (const float4*)latent;
        uint4* dst = (uint4*)labf;
        #pragma unroll
        for (int j = 0; j < 4; j++) {
            int o = j * 131072 + t;
            float4 a0 = src[2 * o];
            float4 a1 = src[2 * o + 1];
            union { ushort u[8]; uint4 v; } pk;
            pk.u[0] = f2bf(a0.x); pk.u[1] = f2bf(a0.y); pk.u[2] = f2bf(a0.z); pk.u[3] = f2bf(a0.w);
            pk.u[4] = f2bf(a1.x); pk.u[5] = f2bf(a1.y); pk.u[6] = f2bf(a1.z); pk.u[7] = f2bf(a1.w);
            dst[o] = pk.v;
        }
        return;
    }

    int t  = blockIdx.x * 256 + threadIdx.x;
    int o  = t % OUT_F;
    int i8 = t / OUT_F;
    const float* src = w + (size_t)(i8 * 8) * OUTB + (size_t)o * 8;

    const float P[8] = {1.f, 2.f, 4.f, 8.f, 16.f, 32.f, 64.f, -128.f};
    float regsum = 0.f;
    union { ushort u[8]; uint4 v; } pk;

    #pragma unroll
    for (int r = 0; r < 8; r++) {
        float4 a = *(const float4*)(src + (size_t)r * OUTB);
        float4 b = *(const float4*)(src + (size_t)r * OUTB + 4);
        float x[8] = {a.x, a.y, a.z, a.w, b.x, b.y, b.z, b.w};
        float iw = 0.f;
        #pragma unroll
        for (int j = 0; j < 8; j++) {
            float p = __builtin_amdgcn_rcpf(1.f + __expf(-x[j]));
            iw += p * P[j];
            regsum += fminf(p, 1.f - p);
        }
        pk.u[r] = f2bf(iw);
    }
    *(uint4*)(wp + ((size_t)i8 * OUT_F + o) * 8) = pk.v;

    float ws = waveReduceSum(regsum);
    __shared__ float red[4];
    int lane = threadIdx.x & 63, wv = threadIdx.x >> 6;
    if (lane == 0) red[wv] = ws;
    __syncthreads();
    if (threadIdx.x == 0) regpart[blockIdx.x] = red[0] + red[1] + red[2] + red[3];
}

// k_gemm: split-K bf16 MFMA GEMM, 64x64 tile, BK=64, double-buffered,
// B staged via global_load_lds. Pure disjoint plane stores — NO fences/atomics.
__global__ __launch_bounds__(256) void k_gemm(const ushort* __restrict__ labf,
                                              const ushort* __restrict__ wp,
                                              float* __restrict__ predp) {
    __shared__ __align__(16) ushort lA[2][64 * 72];   // row stride 72
    __shared__ __align__(16) ushort lB[2][8 * 1032];  // plane stride 1032

    const int tid  = threadIdx.x;
    const int n0   = blockIdx.x * 64;
    const int m0   = blockIdx.y * 64;
    const int bz   = blockIdx.z;
    const int kbase = bz * KSPAN;
    const int kg0   = kbase >> 3;
    const int lane = tid & 63, w = tid >> 6;
    const int wm = w >> 1, wn = w & 1;
    const int quad = lane >> 4, l16 = lane & 15;

    f32x4 acc[2][2] = {{{0.f,0.f,0.f,0.f},{0.f,0.f,0.f,0.f}},
                       {{0.f,0.f,0.f,0.f},{0.f,0.f,0.f,0.f}}};

    const int ar = tid >> 2, ac = tid & 3;            // A: row, 16-elem k-chunk
    const ushort* aptr = labf + (size_t)(m0 + ar) * IN_F + kbase + ac * 16;
    const ushort* bbase = wp + ((size_t)kg0 * OUT_F + n0 + lane) * 8;

    int buf = 0;
    glds16(bbase + (size_t)(2 * w) * OUT_F * 8,     &lB[0][(2 * w) * 1032]);
    glds16(bbase + (size_t)(2 * w + 1) * OUT_F * 8, &lB[0][(2 * w + 1) * 1032]);
    {
        uint4 a0 = *(const uint4*)aptr;
        uint4 a1 = *(const uint4*)(aptr + 8);
        *(uint4*)&lA[0][ar * 72 + ac * 16]     = a0;
        *(uint4*)&lA[0][ar * 72 + ac * 16 + 8] = a1;
    }
    __syncthreads();

    for (int it = 0; it < NIT; ++it) {
        const int nxt = buf ^ 1;
        uint4 a0, a1;
        if (it + 1 < NIT) {
            const ushort* bp = bbase + (size_t)(it + 1) * 8 * OUT_F * 8;
            glds16(bp + (size_t)(2 * w) * OUT_F * 8,     &lB[nxt][(2 * w) * 1032]);
            glds16(bp + (size_t)(2 * w + 1) * OUT_F * 8, &lB[nxt][(2 * w + 1) * 1032]);
            a0 = *(const uint4*)(aptr + (it + 1) * BK);
            a1 = *(const uint4*)(aptr + (it + 1) * BK + 8);
        }
        #pragma unroll
        for (int s = 0; s < 2; ++s) {
            short8 af0 = *(short8*)&lA[buf][(wm * 32 + l16) * 72 + s * 32 + quad * 8];
            short8 af1 = *(short8*)&lA[buf][(wm * 32 + 16 + l16) * 72 + s * 32 + quad * 8];
            short8 bf0 = *(short8*)&lB[buf][(s * 4 + quad) * 1032 + (wn * 32 + l16) * 8];
            short8 bf1 = *(short8*)&lB[buf][(s * 4 + quad) * 1032 + (wn * 32 + 16 + l16) * 8];
            acc[0][0] = __builtin_amdgcn_mfma_f32_16x16x32_bf16(af0, bf0, acc[0][0], 0, 0, 0);
            acc[0][1] = __builtin_amdgcn_mfma_f32_16x16x32_bf16(af0, bf1, acc[0][1], 0, 0, 0);
            acc[1][0] = __builtin_amdgcn_mfma_f32_16x16x32_bf16(af1, bf0, acc[1][0], 0, 0, 0);
            acc[1][1] = __builtin_amdgcn_mfma_f32_16x16x32_bf16(af1, bf1, acc[1][1], 0, 0, 0);
        }
        if (it + 1 < NIT) {
            *(uint4*)&lA[nxt][ar * 72 + ac * 16]     = a0;
            *(uint4*)&lA[nxt][ar * 72 + ac * 16 + 8] = a1;
        }
        __syncthreads();
        buf = nxt;
    }

    float* plane = predp + (size_t)bz * PLANE;
    #pragma unroll
    for (int fm = 0; fm < 2; fm++)
    #pragma unroll
    for (int fn = 0; fn < 2; fn++)
    #pragma unroll
    for (int r = 0; r < 4; r++) {
        int m = m0 + wm * 32 + fm * 16 + quad * 4 + r;
        int n = n0 + wn * 32 + fn * 16 + l16;
        plane[(size_t)m * OUT_F + n] = acc[fm][fn][r];
    }
}

// k_epi: 768 blocks x 256 threads; thread -> 4 consecutive n (one float4 per
// plane, 128B contiguous tsum). Per-block partial -> plain store. NO atomics.
__global__ __launch_bounds__(256) void k_epi(const float* __restrict__ predp,
                                             const float* __restrict__ tsum,
                                             float* __restrict__ sqpart) {
    int g = blockIdx.x * 256 + threadIdx.x;     // float4 index in [0, 196608)
    int m = g / (OUT_F / 4);
    int c = g % (OUT_F / 4);
    const float4* pp = (const float4*)predp;
    float4 p0 = pp[g];
    float4 p1 = pp[g + PLANE4];
    float4 p2 = pp[g + 2 * PLANE4];
    float4 p3 = pp[g + 3 * PLANE4];
    float pv[4] = {p0.x + p1.x + p2.x + p3.x, p0.y + p1.y + p2.y + p3.y,
                   p0.z + p1.z + p2.z + p3.z, p0.w + p1.w + p2.w + p3.w};
    const float* ts = tsum + (size_t)m * OUTB + (size_t)c * 32;
    float lsum = 0.f;
    #pragma unroll
    for (int j = 0; j < 4; j++) {
        float4 t0 = *(const float4*)(ts + j * 8);
        float4 t1 = *(const float4*)(ts + j * 8 + 4);
        float isum = t0.x + 2.f * t0.y + 4.f * t0.z + 8.f * t0.w
                   + 16.f * t1.x + 32.f * t1.y + 64.f * t1.z - 128.f * t1.w;
        float d = pv[j] - isum;
        lsum += d * d;
    }
    float wsum = waveReduceSum(lsum);
    __shared__ float red[4];
    if ((threadIdx.x & 63) == 0) red[threadIdx.x >> 6] = wsum;
    __syncthreads();
    if (threadIdx.x == 0)
        sqpart[blockIdx.x] = red[0] + red[1] + red[2] + red[3];
}

// k_fin: 1 block; reduce regpart[1536] + sqpart[768], write the 3 outputs.
__global__ __launch_bounds__(256) void k_fin(const float* __restrict__ regpart,
                                             const float* __restrict__ sqpart,
                                             float* __restrict__ out) {
    int tid = threadIdx.x;
    float r = 0.f, s = 0.f;
    #pragma unroll
    for (int j = 0; j < 6; j++) r += regpart[tid + j * 256];
    #pragma unroll
    for (int j = 0; j < 3; j++) s += sqpart[tid + j * 256];
    r = waveReduceSum(r);
    s = waveReduceSum(s);
    __shared__ float redR[4], redS[4];
    int lane = tid & 63, wv = tid >> 6;
    if (lane == 0) { redR[wv] = r; redS[wv] = s; }
    __syncthreads();
    if (tid == 0) {
        float R = redR[0] + redR[1] + redR[2] + redR[3];
        float S = redS[0] + redS[1] + redS[2] + redS[3];
        float recon = S / ((float)(BATCH * OUT_F) * 255.f * 255.f);
        float reg   = 0.001f * R / (float)((size_t)IN_F * OUTB);
        out[0] = recon + reg;
        out[1] = recon;
        out[2] = reg;
    }
}

extern "C" void kernel_launch(void* const* d_in, const int* in_sizes, int n_in,
                              void* d_out, int out_size, void* d_ws, size_t ws_size,
                              hipStream_t stream) {
    const float* latent = (const float*)d_in[0];   // [1024, 4096]
    const float* tsum   = (const float*)d_in[1];   // [1024, 6144]
    const float* weight = (const float*)d_in[2];   // [4096, 6144]
    float* out      = (float*)d_out;
    float* predp    = (float*)d_ws;
    ushort* wp      = (ushort*)((char*)d_ws + WS_WP);
    ushort* labf    = (ushort*)((char*)d_ws + WS_LABF);
    float* regpart  = (float*)((char*)d_ws + WS_REGP);
    float* sqpart   = (float*)((char*)d_ws + WS_SQP);

    k_weights<<<2048, 256, 0, stream>>>(weight, latent, wp, labf, regpart);
    k_gemm<<<dim3(OUT_F / 64, BATCH / 64, SPLITK), 256, 0, stream>>>(labf, wp, predp);
    k_epi<<<EPIBLK, 256, 0, stream>>>(predp, tsum, sqpart);
    k_fin<<<1, 256, 0, stream>>>(regpart, sqpart, out);
}